// Round 5
// baseline (244.081 us; speedup 1.0000x reference)
//
#include <hip/hip_runtime.h>
#include <hip/hip_bf16.h>
#include <math.h>

typedef short bf16x8 __attribute__((ext_vector_type(8)));
typedef float f32x4 __attribute__((ext_vector_type(4)));
typedef unsigned int u32;

#define B_DIM 8192
#define H_DIM 1024
#define NPATH 256
#define NSTEP 50

__device__ __forceinline__ void gld_lds16(const void* g, void* lds) {
  __builtin_amdgcn_global_load_lds(
      (const __attribute__((address_space(1))) u32*)g,
      (__attribute__((address_space(3))) u32*)lds, 16, 0, 0);
}

__device__ __forceinline__ void cast4(const float* in, __hip_bfloat16* out, int i) {
  float4 v = ((const float4*)in)[i];
  union { __hip_bfloat16 h[4]; short4 s; } u;
  u.h[0] = __float2bfloat16(v.x);
  u.h[1] = __float2bfloat16(v.y);
  u.h[2] = __float2bfloat16(v.z);
  u.h[3] = __float2bfloat16(v.w);
  ((short4*)out)[i] = u.s;
}

// ---------------- fused prep ----------------
// [0,8192)        cast x -> xb
// [8192,11264)    transpose+cast W_in/W_hid/W_out (1024 32x32 tiles each)
// [11264,11520)   plain cast W_agg -> waggb
// [11520,11524)   v2[d] = sum_h b_agg[h]*W_out[h][d] + b_out[d]
// [11524,11540)   zero wc32
__global__ __launch_bounds__(256) void prep_kernel(
    const float* __restrict__ x, const float* __restrict__ W_in,
    const float* __restrict__ W_hid, const float* __restrict__ W_out,
    const float* __restrict__ W_agg, const float* __restrict__ b_agg,
    const float* __restrict__ b_out,
    __hip_bfloat16* __restrict__ xb, __hip_bfloat16* __restrict__ wtin,
    __hip_bfloat16* __restrict__ wthid, __hip_bfloat16* __restrict__ wtout,
    __hip_bfloat16* __restrict__ waggb, float* __restrict__ v2,
    float* __restrict__ wc32) {
  __shared__ float t[32][33];
  int bid = blockIdx.x, tid = threadIdx.x;
  if (bid < 8192) {
    cast4(x, xb, bid * 256 + tid);
    return;
  }
  if (bid < 11264) {
    int job = bid - 8192;
    const float* W; __hip_bfloat16* Wt;
    if (job < 1024)      { W = W_in;  Wt = wtin; }
    else if (job < 2048) { W = W_hid; Wt = wthid; job -= 1024; }
    else                 { W = W_out; Wt = wtout; job -= 2048; }
    int tX = job & 31, tY = job >> 5;
    int tx = tid & 31, r4 = tid >> 5;
#pragma unroll
    for (int i = 0; i < 4; ++i) {
      int ty = r4 * 4 + i;
      t[ty][tx] = W[(size_t)(tY * 32 + ty) * H_DIM + tX * 32 + tx];
    }
    __syncthreads();
#pragma unroll
    for (int i = 0; i < 4; ++i) {
      int ty = r4 * 4 + i;
      Wt[(size_t)(tX * 32 + ty) * H_DIM + tY * 32 + tx] = __float2bfloat16(t[tx][ty]);
    }
    return;
  }
  if (bid < 11520) {
    cast4(W_agg, waggb, (bid - 11264) * 256 + tid);
    return;
  }
  if (bid < 11524) {
    int d = (bid - 11520) * 256 + tid;
    float s = 0.f;
#pragma unroll 8
    for (int h = 0; h < H_DIM; ++h) s += b_agg[h] * W_out[(size_t)h * H_DIM + d];
    v2[d] = s + b_out[d];
    return;
  }
  // zero wc32 (1024x256 fp32 = 65536 float4), 16 blocks x 256 thr x 16
  int i = (bid - 11524) * 256 + tid;
#pragma unroll
  for (int k = 0; k < 16; ++k)
    ((float4*)wc32)[(size_t)k * 4096 + i] = (float4){0.f, 0.f, 0.f, 0.f};
}

// ------------- fused feedback + endpoints: per block = 4 batch rows -------------
__global__ __launch_bounds__(256) void fb_end_kernel(
    const __hip_bfloat16* __restrict__ h2b, const float* __restrict__ Wfb,
    const float* __restrict__ bfb, const float* __restrict__ ns,
    __hip_bfloat16* __restrict__ eb, float DI, float SQDT) {
  __shared__ float fv[4];
  int wid = threadIdx.x >> 6, lane = threadIdx.x & 63;
  int row = blockIdx.x * 4 + wid;
  const __hip_bfloat16* hrow = h2b + (size_t)row * H_DIM;
  float s = 0.f;
#pragma unroll
  for (int i = lane; i < H_DIM; i += 64) s += __bfloat162float(hrow[i]) * Wfb[i];
#pragma unroll
  for (int off = 32; off > 0; off >>= 1) s += __shfl_down(s, off);
  if (lane == 0) fv[wid] = 1.0f / (1.0f + expf(-(s + bfb[0])));
  __syncthreads();
#pragma unroll
  for (int w = 0; w < 4; ++w) {
    size_t i = (size_t)(blockIdx.x * 4 + w) * NPATH + threadIdx.x;
    eb[i] = __float2bfloat16(fv[w] * DI + SQDT * ns[i]);
  }
}

// ---------------- pipelined 256-row-tile MFMA GEMM core ----------------
// BM=256, BN=TBN, BK=64, 8 waves (2Mx4N). Counted-vmcnt double-buffered staging
// (T3/T4-lite) + LDS XOR swizzle via pre-swizzled global source (T2, rule #21).
// K-loop: DUAL selects source-2 (lda2/ldb2 = 256) for kt >= K1.
template <int TBN, bool DUAL>
__device__ __forceinline__ void kloop(
    const __hip_bfloat16* __restrict__ A, int lda,
    const __hip_bfloat16* __restrict__ Bt, int ldb,
    const __hip_bfloat16* __restrict__ A2, const __hip_bfloat16* __restrict__ Bt2,
    int K, int K1, int bm, int bn, char* smem, f32x4 (*acc)[TBN / 64]) {
  constexpr int NR = TBN / 64;
  constexpr int SMHALF = (256 + TBN) * 64 * 2;
  constexpr int NLOADS = (256 + TBN) / 64;
  const int tid = threadIdx.x;
  const int lane = tid & 63, wid = tid >> 6;
  const int wm = wid >> 2, wn = wid & 3;
  const int frow = lane & 15, kgrp = lane >> 4;

  auto stage = [&](int kt, int d) {
    char* dst = smem + d * SMHALF;
    const __hip_bfloat16 *As_, *Bs_;
    int alda, aldb, akt;
    if (!DUAL || kt < K1) { As_ = A; Bs_ = Bt; alda = lda; aldb = ldb; akt = kt; }
    else { As_ = A2; Bs_ = Bt2; alda = 256; aldb = 256; akt = kt - K1; }
#pragma unroll
    for (int j = 0; j < NLOADS; ++j) {
      int c = j * 512 + tid;
      if (j < 4) {  // A tile: 256x64
        int row = c >> 3, cb = (c & 7) * 16;
        int col = (cb ^ ((row & 7) << 4)) >> 1;
        gld_lds16((const void*)(As_ + (size_t)(bm * 256 + row) * alda + akt + col), dst + c * 16);
      } else {      // B tile: TBN x 64
        int cB = c - 2048;
        int row = cB >> 3, cb = (cB & 7) * 16;
        int col = (cb ^ ((row & 7) << 4)) >> 1;
        gld_lds16((const void*)(Bs_ + (size_t)(bn * TBN + row) * aldb + akt + col), dst + 32768 + cB * 16);
      }
    }
  };

  stage(0, 0);
  const int NT = K >> 6;
  for (int t = 0; t < NT; ++t) {
    const int cur = t & 1;
    if (t + 1 < NT) stage((t + 1) << 6, cur ^ 1);
    if (t == 0 || t + 1 >= NT) {
      asm volatile("s_waitcnt vmcnt(0)" ::: "memory");
    } else if constexpr (TBN == 256) {
      asm volatile("s_waitcnt vmcnt(8)" ::: "memory");
    } else {
      asm volatile("s_waitcnt vmcnt(6)" ::: "memory");
    }
    __builtin_amdgcn_s_barrier();

    const char* Ab = smem + cur * SMHALF;
    const char* Bb = Ab + 32768;
    bf16x8 bfr[NR][2];
#pragma unroll
    for (int n = 0; n < NR; ++n)
#pragma unroll
      for (int s = 0; s < 2; ++s) {
        int row = wn * (NR * 16) + n * 16 + frow;
        int cb = s * 64 + kgrp * 16;
        bfr[n][s] = *(const bf16x8*)(Bb + row * 128 + (cb ^ ((row & 7) << 4)));
      }
#pragma unroll
    for (int mh = 0; mh < 2; ++mh) {
      bf16x8 af[4][2];
#pragma unroll
      for (int m = 0; m < 4; ++m)
#pragma unroll
        for (int s = 0; s < 2; ++s) {
          int row = wm * 128 + (mh * 4 + m) * 16 + frow;
          int cb = s * 64 + kgrp * 16;
          af[m][s] = *(const bf16x8*)(Ab + row * 128 + (cb ^ ((row & 7) << 4)));
        }
#pragma unroll
      for (int m = 0; m < 4; ++m)
#pragma unroll
        for (int n = 0; n < NR; ++n)
#pragma unroll
          for (int s = 0; s < 2; ++s)
            acc[mh * 4 + m][n] = __builtin_amdgcn_mfma_f32_16x16x32_bf16(
                af[m][s], bfr[n][s], acc[mh * 4 + m][n], 0, 0, 0);
    }
    __builtin_amdgcn_s_barrier();
  }
}

// MODE 0: relu(acc+bias)->bf16 ; MODE 3: acc+bias->fp32 ; MODE 4: atomicAdd fp32
// EXTRA 0: none ; 1: Wc split-K tail blocks ; 2: wc cast tail blocks ; 3: DUAL
template <int TBN, int MODE, bool NOISE, int EXTRA>
__global__ __launch_bounds__(512) void gemm8(
    const __hip_bfloat16* __restrict__ A, const __hip_bfloat16* __restrict__ Bt,
    const float* __restrict__ bias, void* __restrict__ out, int N, int K,
    int nGemm, int nNoise,
    const float* __restrict__ noise, float* __restrict__ ns, int rowStart, int rowCount,
    const __hip_bfloat16* __restrict__ wcA, const __hip_bfloat16* __restrict__ wcBt,
    float* __restrict__ wc32, __hip_bfloat16* __restrict__ wcbt,
    const __hip_bfloat16* __restrict__ A2, const __hip_bfloat16* __restrict__ Bt2, int K1) {
  constexpr int NR = TBN / 64;
  constexpr int SMHALF = (256 + TBN) * 64 * 2;
  __shared__ char smem[2 * SMHALF];
  const int bid = blockIdx.x;

  if (NOISE && bid >= nGemm && bid < nGemm + nNoise) {
    int j = bid - nGemm;
    int stride = nNoise * 512;
    for (int r = j * 512 + threadIdx.x; r < rowCount; r += stride) {
      const float2* p = (const float2*)(noise + (size_t)(rowStart + r) * NSTEP);
      float s = 0.f;
#pragma unroll
      for (int i = 0; i < NSTEP / 2; ++i) { float2 v = p[i]; s += v.x + v.y; }
      ns[rowStart + r] = s;
    }
    return;
  }
  if (EXTRA == 2 && bid >= nGemm + nNoise) {
    cast4(wc32, wcbt, (bid - nGemm - nNoise) * 512 + threadIdx.x);
    return;
  }
  if (EXTRA == 1 && bid >= nGemm + nNoise) {
    // Wc split-K: wcT[n][p] = sum_h wtout[n][h]*waggb[p][h], K=1024 in 4 slices
    int wcid = bid - nGemm - nNoise;   // 0..15
    int wbm = wcid & 3, ks = wcid >> 2;
    f32x4 acc[8][NR];
#pragma unroll
    for (int m = 0; m < 8; ++m)
#pragma unroll
      for (int n = 0; n < NR; ++n) acc[m][n] = (f32x4){0.f, 0.f, 0.f, 0.f};
    kloop<TBN, false>(wcA + ks * 256, H_DIM, wcBt + ks * 256, H_DIM,
                      nullptr, nullptr, 256, 0, wbm, 0, smem, acc);
    const int lane = threadIdx.x & 63, wid = threadIdx.x >> 6;
    const int wm = wid >> 2, wn = wid & 3;
    const int frow = lane & 15, kgrp = lane >> 4;
    const int r0 = wbm * 256 + wm * 128, c0 = wn * (NR * 16);
#pragma unroll
    for (int n = 0; n < NR; ++n) {
      int col = c0 + n * 16 + frow;
#pragma unroll
      for (int m = 0; m < 8; ++m)
#pragma unroll
        for (int j = 0; j < 4; ++j)
          atomicAdd(wc32 + (size_t)(r0 + m * 16 + kgrp * 4 + j) * NPATH + col, acc[m][n][j]);
    }
    return;
  }

  const int gx = N / TBN;
  const int bm = bid / gx, bn = bid % gx;
  f32x4 acc[8][NR];
#pragma unroll
  for (int m = 0; m < 8; ++m)
#pragma unroll
    for (int n = 0; n < NR; ++n) acc[m][n] = (f32x4){0.f, 0.f, 0.f, 0.f};
  kloop<TBN, EXTRA == 3>(A, K1 ? H_DIM : K, Bt, K1 ? H_DIM : K, A2, Bt2, K, K1, bm, bn, smem, acc);

  const int lane = threadIdx.x & 63, wid = threadIdx.x >> 6;
  const int wm = wid >> 2, wn = wid & 3;
  const int frow = lane & 15, kgrp = lane >> 4;
  const int r0 = bm * 256 + wm * 128;
  const int c0 = bn * TBN + wn * (NR * 16);
#pragma unroll
  for (int n = 0; n < NR; ++n) {
    int col = c0 + n * 16 + frow;
    float bv = bias[col];
#pragma unroll
    for (int m = 0; m < 8; ++m)
#pragma unroll
      for (int j = 0; j < 4; ++j) {
        int row = r0 + m * 16 + kgrp * 4 + j;
        float v = acc[m][n][j] + bv;
        if (MODE == 0) {
          v = fmaxf(v, 0.f);
          ((__hip_bfloat16*)out)[(size_t)row * N + col] = __float2bfloat16(v);
        } else {
          ((float*)out)[(size_t)row * N + col] = v;
        }
      }
  }
}

extern "C" void kernel_launch(void* const* d_in, const int* in_sizes, int n_in,
                              void* d_out, int out_size, void* d_ws, size_t ws_size,
                              hipStream_t stream) {
  (void)in_sizes; (void)n_in; (void)out_size; (void)ws_size;
  const float* x     = (const float*)d_in[0];
  const float* W_in  = (const float*)d_in[1];
  const float* b_in  = (const float*)d_in[2];
  const float* W_hid = (const float*)d_in[3];
  const float* b_hid = (const float*)d_in[4];
  const float* W_fb  = (const float*)d_in[5];
  const float* b_fb  = (const float*)d_in[6];
  const float* W_agg = (const float*)d_in[7];
  const float* b_agg = (const float*)d_in[8];
  const float* W_out = (const float*)d_in[9];
  const float* b_out = (const float*)d_in[10];
  const float* noise = (const float*)d_in[11];

  const int B = B_DIM, H = H_DIM, P = NPATH;
  const int R = B * P;

  size_t off = 0;
  char* base = (char*)d_ws;
  auto take = [&](size_t bytes) -> char* {
    char* r = base + off;
    off = (off + bytes + 255) & ~(size_t)255;
    return r;
  };
  __hip_bfloat16* xb    = (__hip_bfloat16*)take((size_t)B * H * 2);
  __hip_bfloat16* h1b   = (__hip_bfloat16*)take((size_t)B * H * 2);
  __hip_bfloat16* h2b   = (__hip_bfloat16*)take((size_t)B * H * 2);
  __hip_bfloat16* wtin  = (__hip_bfloat16*)take((size_t)H * H * 2);
  __hip_bfloat16* wthid = (__hip_bfloat16*)take((size_t)H * H * 2);
  __hip_bfloat16* wtout = (__hip_bfloat16*)take((size_t)H * H * 2);
  __hip_bfloat16* waggb = (__hip_bfloat16*)take((size_t)P * H * 2);
  __hip_bfloat16* wcbt  = (__hip_bfloat16*)take((size_t)H * P * 2);
  float* wc32 = (float*)take((size_t)H * P * 4);
  float* v2   = (float*)take((size_t)H * 4);
  float* ns   = (float*)take((size_t)R * 4);
  __hip_bfloat16* eb = (__hip_bfloat16*)take((size_t)R * 2);

  float dt = 1.0f / NSTEP;
  float DI = 0.f;
  for (int j = 0; j < NSTEP; ++j) DI += expf(-0.1f * ((float)j * dt));
  DI *= dt;
  float SQDT = sqrtf(dt);

  prep_kernel<<<11540, 256, 0, stream>>>(x, W_in, W_hid, W_out, W_agg, b_agg, b_out,
                                         xb, wtin, wthid, wtout, waggb, v2, wc32);

  // stage1: x@W_in (relu) | noise half 1 | Wc split-K (16 blocks)
  gemm8<256, 0, true, 1><<<400, 512, 0, stream>>>(
      xb, wtin, b_in, h1b, H, H, 128, 256, noise, ns, 0, R / 2,
      wtout, waggb, wc32, nullptr, nullptr, nullptr, 0);
  // stage2: h1@W_hid (relu) | noise half 2 | wc32 -> wcbt cast (128 blocks)
  gemm8<256, 0, true, 2><<<512, 512, 0, stream>>>(
      h1b, wthid, b_hid, h2b, H, H, 128, 256, noise, ns, R / 2, R - R / 2,
      nullptr, nullptr, wc32, wcbt, nullptr, nullptr, 0);
  fb_end_kernel<<<B / 4, 256, 0, stream>>>(h2b, W_fb, b_fb, ns, eb, DI, SQDT);
  // final: [h2|eb] @ [wtout;wcbt]^T + v2 -> fp32, K=1280 dual-source
  gemm8<128, 3, false, 3><<<256, 512, 0, stream>>>(
      h2b, wtout, v2, d_out, H, 1280, 256, 0, nullptr, nullptr, 0, 0,
      nullptr, nullptr, nullptr, nullptr, eb, wcbt, H);
}